// Round 1
// baseline (515.009 us; speedup 1.0000x reference)
//
#include <hip/hip_runtime.h>
#include <stdint.h>

#define N_NODES_C 50000
#define N_EDGES_C 1000000
#define NODE_DIM_C 128
#define EDGE_DIM_C 64

typedef __attribute__((ext_vector_type(8))) short short8;
typedef __attribute__((ext_vector_type(4))) float floatx4;

__device__ __forceinline__ short f2bf(float f) {
    union { float f; uint32_t u; } v; v.f = f;
    uint32_t u = v.u;
    uint32_t r = (u + 0x7FFFu + ((u >> 16) & 1u)) >> 16;  // RNE
    return (short)r;
}

__device__ __forceinline__ float gelu_tanh(float x) {
    // jax.nn.gelu default (approximate=True): 0.5x(1+tanh(sqrt(2/pi)(x+0.044715x^3)))
    //  == x * sigmoid(2*sqrt(2/pi)*(x + 0.044715 x^3))
    float u = x * x;
    float inner = x * (1.0f + 0.044715f * u);
    float z = 1.5957691216057308f * inner;
    float ez = __expf(-z);
    return x / (1.0f + ez);
}

// ---------------- Kernel 1: node projections xs = x@Ws^T+bs, xt = x@Wt^T+bt ----
__global__ __launch_bounds__(256) void node_proj_kernel(
    const float* __restrict__ x,
    const float* __restrict__ Ws, const float* __restrict__ bs,
    const float* __restrict__ Wt, const float* __restrict__ bt,
    float* __restrict__ xs, float* __restrict__ xt)
{
    // B fragments for mfma_f32_16x16x32_bf16: B[k][n], n=lane&15, k=(lane>>4)*8+i
    __shared__ __align__(16) short ws_frag[4][4][64][8];  // [ntile][kstep][lane][i]
    __shared__ __align__(16) short wt_frag[4][4][64][8];

    const int tid = threadIdx.x;
    for (int eidx = tid; eidx < 1024; eidx += 256) {
        int t = eidx >> 8;
        int s = (eidx >> 6) & 3;
        int l = eidx & 63;
        int n = t * 16 + (l & 15);
        int kb = s * 32 + ((l >> 4) << 3);
        const float* wsr = Ws + n * NODE_DIM_C + kb;
        const float* wtr = Wt + n * NODE_DIM_C + kb;
#pragma unroll
        for (int i = 0; i < 8; ++i) {
            ws_frag[t][s][l][i] = f2bf(wsr[i]);
            wt_frag[t][s][l][i] = f2bf(wtr[i]);
        }
    }
    __syncthreads();

    const int wave = tid >> 6, lane = tid & 63;
    const int m = lane & 15, q = lane >> 4;
    const int base = blockIdx.x * 64 + wave * 16;
    const int arow = base + m;

    floatx4 accS[4], accT[4];
    const floatx4 zero = {0.f, 0.f, 0.f, 0.f};
#pragma unroll
    for (int t = 0; t < 4; ++t) { accS[t] = zero; accT[t] = zero; }

#pragma unroll
    for (int s = 0; s < 4; ++s) {
        short8 a;
        if (arow < N_NODES_C) {
            const float4* ap = (const float4*)(x + arow * NODE_DIM_C + s * 32 + q * 8);
            float4 a0 = ap[0], a1 = ap[1];
            a[0] = f2bf(a0.x); a[1] = f2bf(a0.y); a[2] = f2bf(a0.z); a[3] = f2bf(a0.w);
            a[4] = f2bf(a1.x); a[5] = f2bf(a1.y); a[6] = f2bf(a1.z); a[7] = f2bf(a1.w);
        } else {
#pragma unroll
            for (int i = 0; i < 8; ++i) a[i] = 0;
        }
#pragma unroll
        for (int t = 0; t < 4; ++t) {
            short8 bS = *(const short8*)ws_frag[t][s][lane];
            short8 bT = *(const short8*)wt_frag[t][s][lane];
            accS[t] = __builtin_amdgcn_mfma_f32_16x16x32_bf16(a, bS, accS[t], 0, 0, 0);
            accT[t] = __builtin_amdgcn_mfma_f32_16x16x32_bf16(a, bT, accT[t], 0, 0, 0);
        }
    }

#pragma unroll
    for (int t = 0; t < 4; ++t) {
        int col = t * 16 + m;
        float bsv = bs[col], btv = bt[col];
#pragma unroll
        for (int r = 0; r < 4; ++r) {
            int n = base + q * 4 + r;
            if (n < N_NODES_C) {
                xs[n * EDGE_DIM_C + col] = accS[t][r] + bsv;
                xt[n * EDGE_DIM_C + col] = accT[t][r] + btv;
            }
        }
    }
}

// ---------------- Kernel 2: fused edge MLP --------------------------------------
__global__ __launch_bounds__(256) void edge_mlp_kernel(
    const float* __restrict__ ea, const int* __restrict__ ei,
    const float* __restrict__ We, const float* __restrict__ be,
    const float* __restrict__ W1, const float* __restrict__ b1,
    const float* __restrict__ xs, const float* __restrict__ xt,
    float* __restrict__ out)
{
    __shared__ __align__(16) short we_frag[4][2][64][8];  // 8 KB
    __shared__ __align__(16) short w1_frag[4][2][64][8];  // 8 KB
    __shared__ __align__(16) short pbuf[4][16][72];       // per-wave gelu tile, padded

    const int tid = threadIdx.x;
    for (int eidx = tid; eidx < 512; eidx += 256) {
        int t = eidx >> 7;
        int s = (eidx >> 6) & 1;
        int l = eidx & 63;
        int n = t * 16 + (l & 15);
        int kb = s * 32 + ((l >> 4) << 3);
        const float* wer = We + n * EDGE_DIM_C + kb;
        const float* w1r = W1 + n * EDGE_DIM_C + kb;
#pragma unroll
        for (int i = 0; i < 8; ++i) {
            we_frag[t][s][l][i] = f2bf(wer[i]);
            w1_frag[t][s][l][i] = f2bf(w1r[i]);
        }
    }
    __syncthreads();

    const int wave = tid >> 6, lane = tid & 63;
    const int m = lane & 15, q = lane >> 4;
    const int* __restrict__ src = ei;
    const int* __restrict__ tgt = ei + N_EDGES_C;

    float bev[4], b1v[4];
#pragma unroll
    for (int t = 0; t < 4; ++t) { bev[t] = be[t * 16 + m]; b1v[t] = b1[t * 16 + m]; }

    const floatx4 zero = {0.f, 0.f, 0.f, 0.f};
    const int nchunks = N_EDGES_C / 64;  // 15625, exact

    for (int chunk = blockIdx.x; chunk < nchunks; chunk += gridDim.x) {
        const int base = chunk * 64 + wave * 16;

        // GEMM1: e1 = ea @ We^T  (A straight from global, no LDS staging)
        floatx4 acc[4];
#pragma unroll
        for (int t = 0; t < 4; ++t) acc[t] = zero;
#pragma unroll
        for (int s = 0; s < 2; ++s) {
            const float4* ap = (const float4*)(ea + (base + m) * EDGE_DIM_C + s * 32 + q * 8);
            float4 a0 = ap[0], a1 = ap[1];
            short8 a;
            a[0] = f2bf(a0.x); a[1] = f2bf(a0.y); a[2] = f2bf(a0.z); a[3] = f2bf(a0.w);
            a[4] = f2bf(a1.x); a[5] = f2bf(a1.y); a[6] = f2bf(a1.z); a[7] = f2bf(a1.w);
#pragma unroll
            for (int t = 0; t < 4; ++t) {
                short8 b = *(const short8*)we_frag[t][s][lane];
                acc[t] = __builtin_amdgcn_mfma_f32_16x16x32_bf16(a, b, acc[t], 0, 0, 0);
            }
        }

        // epilogue 1: + be + xs[src] + xt[tgt], gelu, write bf16 tile to LDS
        int sidx[4], tidx[4];
#pragma unroll
        for (int r = 0; r < 4; ++r) {
            int e = base + q * 4 + r;
            int si = src[e], ti = tgt[e];
            sidx[r] = min(max(si, 0), N_NODES_C - 1);  // safety clamp
            tidx[r] = min(max(ti, 0), N_NODES_C - 1);
        }
#pragma unroll
        for (int t = 0; t < 4; ++t) {
            int col = t * 16 + m;
#pragma unroll
            for (int r = 0; r < 4; ++r) {
                float c = acc[t][r] + bev[t]
                        + xs[sidx[r] * EDGE_DIM_C + col]
                        + xt[tidx[r] * EDGE_DIM_C + col];
                pbuf[wave][q * 4 + r][col] = f2bf(gelu_tanh(c));
            }
        }

        // GEMM2: out = gelu_e @ W1^T  (A from wave-private LDS, C->A transform)
        floatx4 acc2[4];
#pragma unroll
        for (int t = 0; t < 4; ++t) acc2[t] = zero;
#pragma unroll
        for (int s = 0; s < 2; ++s) {
            short8 a2 = *(const short8*)&pbuf[wave][m][s * 32 + q * 8];
#pragma unroll
            for (int t = 0; t < 4; ++t) {
                short8 b = *(const short8*)w1_frag[t][s][lane];
                acc2[t] = __builtin_amdgcn_mfma_f32_16x16x32_bf16(a2, b, acc2[t], 0, 0, 0);
            }
        }

        // store (+ b1)
#pragma unroll
        for (int t = 0; t < 4; ++t) {
            int col = t * 16 + m;
#pragma unroll
            for (int r = 0; r < 4; ++r) {
                int e = base + q * 4 + r;
                out[e * EDGE_DIM_C + col] = acc2[t][r] + b1v[t];
            }
        }
    }
}

extern "C" void kernel_launch(void* const* d_in, const int* in_sizes, int n_in,
                              void* d_out, int out_size, void* d_ws, size_t ws_size,
                              hipStream_t stream) {
    const float* x   = (const float*)d_in[0];
    const int*   ei  = (const int*)d_in[1];
    const float* ea  = (const float*)d_in[2];
    const float* We  = (const float*)d_in[3];
    const float* be  = (const float*)d_in[4];
    const float* Ws  = (const float*)d_in[5];
    const float* bs  = (const float*)d_in[6];
    const float* Wt  = (const float*)d_in[7];
    const float* bt  = (const float*)d_in[8];
    const float* W1  = (const float*)d_in[9];
    const float* b1  = (const float*)d_in[10];
    float* out = (float*)d_out;

    float* xs = (float*)d_ws;                       // 50000*64 fp32 = 12.8 MB
    float* xt = xs + (size_t)N_NODES_C * EDGE_DIM_C; // +12.8 MB

    dim3 blk(256);
    dim3 grid_nodes((N_NODES_C + 63) / 64);  // 782
    node_proj_kernel<<<grid_nodes, blk, 0, stream>>>(x, Ws, bs, Wt, bt, xs, xt);

    dim3 grid_edges(3125);  // 15625 chunks of 64 edges, 5 per block
    edge_mlp_kernel<<<grid_edges, blk, 0, stream>>>(ea, ei, We, be, W1, b1, xs, xt, out);
}